// Round 7
// baseline (98.002 us; speedup 1.0000x reference)
//
#include <hip/hip_runtime.h>
#include <math.h>

#define N 8192
#define D 64

typedef short bf16x8 __attribute__((ext_vector_type(8)));
typedef float f32x4 __attribute__((ext_vector_type(4)));

__device__ __forceinline__ void gload_lds16(const void* g, void* l) {
    __builtin_amdgcn_global_load_lds(
        (const __attribute__((address_space(1))) void*)g,
        (__attribute__((address_space(3))) void*)l, 16, 0, 0);
}

// Convert fp32 -> bf16 of (sqrt(log2e)*x); nscl[i] = 0.5*||bf16(s*x)||^2 = log2e*||x||^2/2.
// MFMA on scaled inputs gives log2e*(a.b); exp(-(na+nb-2ab)/2) = exp2(ab' - na' - nb').
// Block 0 also zeroes the accumulator slots + completion counter (8 floats).
__global__ __launch_bounds__(256) void convert_norm(
        const float* __restrict__ X, const float* __restrict__ Y,
        const float* __restrict__ Z,
        unsigned short* __restrict__ bmat, float* __restrict__ nscl,
        float* __restrict__ accs) {
    if (blockIdx.x == 0 && threadIdx.x < 8) accs[threadIdx.x] = 0.0f;
    int wid  = blockIdx.x * 4 + (threadIdx.x >> 6);
    int lane = threadIdx.x & 63;
    int mat  = wid >> 13;
    int row  = wid & 8191;
    const float* src = (mat == 0) ? X : (mat == 1 ? Y : Z);
    float v = src[row * D + lane] * 1.2011224087864498f;  // sqrt(log2(e))
    unsigned int bits = __builtin_bit_cast(unsigned int, v);
    unsigned short us = (unsigned short)((bits + 0x7FFFu + ((bits >> 16) & 1u)) >> 16);
    float f = __builtin_bit_cast(float, (unsigned int)us << 16);
    bmat[(size_t)mat * (N * D) + row * D + lane] = us;
    float sq = f * f;
    #pragma unroll
    for (int off = 32; off; off >>= 1) sq += __shfl_xor(sq, off);
    if (lane == 0) nscl[mat * N + row] = sq * 0.5f;
}

// Block: 64 rows x 4096 cols of one pair; 64 iters of 64-col tiles (8 KB).
// Cooperative staging into TRIPLE-buffered LDS (XOR swizzle), synced per iter
// by s_waitcnt vmcnt(2) + raw s_barrier (stage loads stay in flight across
// the barrier). cb (col-norm) values register-prefetched one iter ahead so
// no VMEM latency sits on the MFMA critical path. Per-iter VMEM order is
// [cb_next x2, stage x2] -> vmcnt(2) at iter top retires cb_t + tile-t stage.
// Negligible tiles (all acc < -25, i.e. every term < 3e-8; realized skipped
// mass ~1e-8 vs raw-sum tolerance ~1e2) skip the exp epilogue.
// The LAST block to finish computes the final scalar (atomic counter).
__global__ __launch_bounds__(256, 6) void gram_kernel(
        const unsigned short* __restrict__ bmat,
        const float* __restrict__ nscl,
        float* accs, unsigned int* cnt, float* out) {
    const int PA[6] = {0, 2, 0, 0, 1, 1};  // X,Z,X,X,Y,Y
    const int PB[6] = {0, 2, 2, 1, 1, 2};  // X,Z,Z,Y,Y,Z
    int p  = blockIdx.y;
    int bx = blockIdx.x;          // 0..255
    int ti = bx >> 1;             // row strip (64 rows)
    int tc = bx & 1;              // col half (4096 cols)

    const unsigned short* A = bmat + (size_t)PA[p] * (N * D);
    const unsigned short* B = bmat + (size_t)PB[p] * (N * D);
    const float* ca = nscl + PA[p] * N;
    const float* cb = nscl + PB[p] * N;

    int tid = threadIdx.x;
    int w = tid >> 6, lane = tid & 63;
    int wr = w >> 1, wc = w & 1;
    int rowBase = ti * 64 + wr * 32;
    int r = lane & 15, q = lane >> 4, r7 = lane & 7;

    __shared__ __align__(128) char lds[3 * 8192];   // triple-buffered 8 KB tiles
    __shared__ float wsum[4];

    // Staging: tile = 64 cols x 128 B contiguous; wave w stages sub-region.
    int sub = w * 2048;
    int laneoff = ((lane >> 3) << 7) + ((r7 ^ (lane >> 3)) << 4);
    const char* gB = (const char*)(B + (size_t)(tc * 4096) * D);

    // Swizzled ds_read offsets: phys(col,slot) holds global slot^(col&7)
    int off0 = wc * 4096 + r * 128 + ((q ^ r7) << 4);        // kc=0
    int off1 = wc * 4096 + r * 128 + (((4 + q) ^ r7) << 4);  // kc=1

    // Loop-invariant A fragments and negated row-norm constants (VMEM issued
    // FIRST so the steady-state vmcnt ledger is exact from iter 0).
    bf16x8 afrag[2][2];
    #pragma unroll
    for (int mt = 0; mt < 2; ++mt)
        #pragma unroll
        for (int kc = 0; kc < 2; ++kc)
            afrag[mt][kc] = *reinterpret_cast<const bf16x8*>(
                A + (size_t)(rowBase + mt * 16 + r) * D + kc * 32 + q * 8);
    f32x4 ncam[2];
    #pragma unroll
    for (int mt = 0; mt < 2; ++mt)
        #pragma unroll
        for (int e = 0; e < 4; ++e)
            ncam[mt][e] = -ca[rowBase + mt * 16 + q * 4 + e];

    const float* cbp = cb + tc * 4096 + wc * 32 + r;

    // Prologue VMEM order: S0(2), C0(2), S1(2) -> iter-0 vmcnt(2) leaves S1.
    {
        const char* g0 = gB + sub + laneoff;
        gload_lds16(g0,        lds + sub);
        gload_lds16(g0 + 1024, lds + sub + 1024);
    }
    float cbc0 = cbp[0], cbc1 = cbp[16];
    {
        const char* g1 = gB + 8192 + sub + laneoff;
        gload_lds16(g1,        lds + 8192 + sub);
        gload_lds16(g1 + 1024, lds + 8192 + sub + 1024);
    }

    f32x4 lsum = (f32x4)0.0f;
    unsigned rb = 0;   // read-buffer byte offset: 0 / 8192 / 16384

    for (int t = 0; t < 64; ++t) {
        // Tile t landed when all but the newest 2 VMEM events (last iter's
        // stage pair) retired; barrier publishes it block-wide.
        asm volatile("s_waitcnt vmcnt(2)" ::: "memory");
        __builtin_amdgcn_s_barrier();
        asm volatile("" ::: "memory");

        float cb0 = cbc0, cb1 = cbc1;

        // C_{t+1}: issue cb prefetch FIRST (ledger), clamped at the end
        const float* cbn = cbp + ((t < 63) ? 64 : 0);
        cbc0 = cbn[0]; cbc1 = cbn[16];
        __builtin_amdgcn_sched_barrier(0);   // keep C-before-S issue order

        // S_{t+2}: stage into buffer (t+2)%3 (clamped re-stage keeps the
        // ledger uniform; its buffer is never read again).
        unsigned sb = rb + 16384; if (sb >= 24576) sb -= 24576;
        int tn = (t + 2 <= 63) ? (t + 2) : 63;
        const char* gs = gB + (size_t)tn * 8192 + sub + laneoff;
        gload_lds16(gs,        lds + sb + sub);
        gload_lds16(gs + 1024, lds + sb + sub + 1024);

        const char* lb = lds + rb;
        bf16x8 bfrag[2][2];
        bfrag[0][0] = *reinterpret_cast<const bf16x8*>(lb + off0);
        bfrag[0][1] = *reinterpret_cast<const bf16x8*>(lb + off1);
        bfrag[1][0] = *reinterpret_cast<const bf16x8*>(lb + 2048 + off0);
        bfrag[1][1] = *reinterpret_cast<const bf16x8*>(lb + 2048 + off1);

        // C-init carries the norm bias: acc = -(na + nb); result = log2(term)
        f32x4 acc[2][2];
        acc[0][0] = ncam[0] - cb0; acc[0][1] = ncam[0] - cb1;
        acc[1][0] = ncam[1] - cb0; acc[1][1] = ncam[1] - cb1;

        #pragma unroll
        for (int kc = 0; kc < 2; ++kc)
            #pragma unroll
            for (int mt = 0; mt < 2; ++mt)
                #pragma unroll
                for (int nt = 0; nt < 2; ++nt)
                    acc[mt][nt] = __builtin_amdgcn_mfma_f32_16x16x32_bf16(
                        afrag[mt][kc], bfrag[nt][kc], acc[mt][nt], 0, 0, 0);

        // Negligible-tile skip (max3-fusable tree over the 16 lane values)
        float m0 = fmaxf(fmaxf(acc[0][0][0], acc[0][0][1]), acc[0][0][2]);
        float m1 = fmaxf(fmaxf(acc[0][0][3], acc[0][1][0]), acc[0][1][1]);
        float m2 = fmaxf(fmaxf(acc[0][1][2], acc[0][1][3]), acc[1][0][0]);
        float m3 = fmaxf(fmaxf(acc[1][0][1], acc[1][0][2]), acc[1][0][3]);
        float m4 = fmaxf(fmaxf(acc[1][1][0], acc[1][1][1]), acc[1][1][2]);
        float m5 = fmaxf(fmaxf(m0, m1), m2);
        float m6 = fmaxf(fmaxf(m3, m4), acc[1][1][3]);
        float m  = fmaxf(m5, m6);

        if (__any(m > -25.0f)) {
            #pragma unroll
            for (int mt = 0; mt < 2; ++mt) {
                #pragma unroll
                for (int nt = 0; nt < 2; ++nt) {
                    f32x4 ex;
                    #pragma unroll
                    for (int e = 0; e < 4; ++e)
                        ex[e] = __builtin_amdgcn_exp2f(acc[mt][nt][e]);
                    lsum += ex;
                }
            }
        }

        cbp += 64;
        rb += 8192; if (rb >= 24576) rb = 0;
    }

    float ls = lsum[0] + lsum[1] + lsum[2] + lsum[3];
    #pragma unroll
    for (int off = 32; off; off >>= 1) ls += __shfl_xor(ls, off);
    if (lane == 0) wsum[w] = ls;
    __syncthreads();
    if (tid == 0) {
        atomicAdd(&accs[p], wsum[0] + wsum[1] + wsum[2] + wsum[3]);
        __threadfence();
        unsigned old = atomicAdd(cnt, 1u);
        if (old == 6 * 256 - 1) {
            // last block: all accs atomics are globally visible; read them
            // coherently via atomic RMW (cross-XCD safe) and finalize.
            __threadfence();
            double s[6];
            #pragma unroll
            for (int i = 0; i < 6; ++i) s[i] = (double)atomicAdd(&accs[i], 0.0f);
            double inv = 1.0 / (8192.0 * 8192.0 * 3.5449077018110318);
            double mxx = s[0] * inv, mzz = s[1] * inv, mxz = s[2] * inv;
            double mxy = s[3] * inv, myy = s[4] * inv, myz = s[5] * inv;
            double r1 = log(3.0 * sqrt(mxx * mzz + 1e-5) / (mxz + 1e-5));
            double r2 = log(3.0 * sqrt(myy * mzz + 1e-5) / (myz + 1e-5));
            double r3 = log(3.0 * sqrt(mxx * myy + 1e-5) / (mxy + 1e-5));
            out[0] = (float)(10.0 * r1 + r2 + 10.0 * r3);
        }
    }
}

extern "C" void kernel_launch(void* const* d_in, const int* in_sizes, int n_in,
                              void* d_out, int out_size, void* d_ws, size_t ws_size,
                              hipStream_t stream) {
    const float* X = (const float*)d_in[0];
    const float* Y = (const float*)d_in[1];
    const float* Z = (const float*)d_in[2];
    char* ws = (char*)d_ws;
    unsigned short* bmat = (unsigned short*)ws;                       // 3 MB
    float* nscl = (float*)(ws + (size_t)3 * N * D * 2);               // 3*8192 f32
    float* accs = (float*)(ws + (size_t)3 * N * D * 2 + (size_t)3 * N * 4); // 8 slots
    unsigned int* cnt = (unsigned int*)(accs + 6);
    float* out = (float*)d_out;

    hipLaunchKernelGGL(convert_norm, dim3(3 * N / 4), dim3(256), 0, stream,
                       X, Y, Z, bmat, nscl, accs);
    hipLaunchKernelGGL(gram_kernel, dim3(256, 6), dim3(256), 0, stream,
                       bmat, nscl, accs, cnt, out);
}

// Round 8
// 85.547 us; speedup vs baseline: 1.1456x; 1.1456x over previous
//
#include <hip/hip_runtime.h>
#include <math.h>

#define N 8192
#define D 64

typedef short bf16x8 __attribute__((ext_vector_type(8)));
typedef float f32x4 __attribute__((ext_vector_type(4)));

__device__ __forceinline__ void gload_lds16(const void* g, void* l) {
    __builtin_amdgcn_global_load_lds(
        (const __attribute__((address_space(1))) void*)g,
        (__attribute__((address_space(3))) void*)l, 16, 0, 0);
}

// Convert fp32 -> bf16 of (sqrt(log2e)*x); nscl[i] = 0.5*||bf16(s*x)||^2 = log2e*||x||^2/2.
// MFMA on scaled inputs gives log2e*(a.b); exp(-(na+nb-2ab)/2) = exp2(ab' - na' - nb').
// Block 0 also zeroes the accumulator slots + completion counter (8 floats).
__global__ __launch_bounds__(256) void convert_norm(
        const float* __restrict__ X, const float* __restrict__ Y,
        const float* __restrict__ Z,
        unsigned short* __restrict__ bmat, float* __restrict__ nscl,
        float* __restrict__ accs) {
    if (blockIdx.x == 0 && threadIdx.x < 8) accs[threadIdx.x] = 0.0f;
    int wid  = blockIdx.x * 4 + (threadIdx.x >> 6);
    int lane = threadIdx.x & 63;
    int mat  = wid >> 13;
    int row  = wid & 8191;
    const float* src = (mat == 0) ? X : (mat == 1 ? Y : Z);
    float v = src[row * D + lane] * 1.2011224087864498f;  // sqrt(log2(e))
    unsigned int bits = __builtin_bit_cast(unsigned int, v);
    unsigned short us = (unsigned short)((bits + 0x7FFFu + ((bits >> 16) & 1u)) >> 16);
    float f = __builtin_bit_cast(float, (unsigned int)us << 16);
    bmat[(size_t)mat * (N * D) + row * D + lane] = us;
    float sq = f * f;
    #pragma unroll
    for (int off = 32; off; off >>= 1) sq += __shfl_xor(sq, off);
    if (lane == 0) nscl[mat * N + row] = sq * 0.5f;
}

// 1152 blocks. Cross-pairs (XZ,XY,YZ): 256 blocks each = (row strip, col half),
// 64 tiles of 64x64. Self-pairs (XX,ZZ,YY): upper-triangle only, weight 2 off
// the tile-diagonal / 1 on it; row strip i is paired with mirror strip 127-i
// (combined length 129 tiles) and split into two ~64-tile blocks. Each block
// runs 1-2 contiguous (strip,j) segments through ONE triple-buffered LDS
// pipeline (XOR swizzle, vmcnt(2)+raw-barrier, stage lookahead via the global
// tile->j map). Strip-B A-fragments load at the seam (no VGPR overlap).
// Negligible tiles (all acc < -25) skip the exp epilogue.
// The LAST block to finish computes the final scalar (atomic counter).
__global__ __launch_bounds__(256, 6) void gram_kernel(
        const unsigned short* __restrict__ bmat,
        const float* __restrict__ nscl,
        float* accs, unsigned int* cnt, float* out) {
    const int PA[6] = {0, 2, 0, 0, 1, 1};  // X,Z,X,X,Y,Y
    const int PB[6] = {0, 2, 2, 1, 1, 2};  // X,Z,Z,Y,Y,Z

    int bx = blockIdx.x;
    int p, stripA, jA0, nA, stripB, jB0, nTot, diagU;
    float wBase;
    if (bx < 768) {                       // cross pairs: full grid
        int pc = bx >> 8;                 // 0,1,2 -> p = 2,3,5
        p = (pc == 0) ? 2 : ((pc == 1) ? 3 : 5);
        int bi = bx & 255;
        stripA = bi >> 1; jA0 = (bi & 1) << 6; nA = 64;
        stripB = stripA;  jB0 = 0;          nTot = 64; diagU = -1; wBase = 1.0f;
    } else {                              // self pairs: balanced triangle
        int sx = bx - 768;
        int ps = sx >> 7;                 // 0,1,2 -> p = 0,1,4
        p = (ps == 0) ? 0 : ((ps == 1) ? 1 : 4);
        int bi = sx & 127; int i = bi >> 1, h = bi & 1;
        int mi = 127 - i;
        if (h == 0) { stripA = i; jA0 = i;      nA = 65;     stripB = i;  jB0 = 0;  nTot = 65; diagU = 0; }
        else        { stripA = i; jA0 = i + 65; nA = 63 - i; stripB = mi; jB0 = mi; nTot = 64; diagU = nA; }
        wBase = 2.0f;
    }

    const unsigned short* A = bmat + (size_t)PA[p] * (N * D);
    const unsigned short* B = bmat + (size_t)PB[p] * (N * D);
    const float* ca = nscl + PA[p] * N;
    const float* cb = nscl + PB[p] * N;

    int tid = threadIdx.x;
    int w = tid >> 6, lane = tid & 63;
    int wr = w >> 1, wc = w & 1;
    int r = lane & 15, q = lane >> 4, r7 = lane & 7;

    __shared__ __align__(128) char lds[3 * 8192];   // triple-buffered 8 KB tiles
    __shared__ float wsum[4];

    // Staging: tile = 64 cols x 128 B contiguous; wave w stages its 2 KB.
    int sub = w * 2048;
    int laneoff = ((lane >> 3) << 7) + ((r7 ^ (lane >> 3)) << 4);
    const char* gBmat = (const char*)B;

    // Swizzled ds_read offsets: phys(col,slot) holds global slot^(col&7)
    int off0 = wc * 4096 + r * 128 + ((q ^ r7) << 4);        // kc=0
    int off1 = wc * 4096 + r * 128 + (((4 + q) ^ r7) << 4);  // kc=1

    auto tileJ = [&](int u) { return (u < nA) ? (jA0 + u) : (jB0 + (u - nA)); };

    // Prologue: stage tiles 0,1 into bufs 0,1
    {
        const char* g0 = gBmat + (size_t)tileJ(0) * 8192 + sub + laneoff;
        gload_lds16(g0,        lds + sub);
        gload_lds16(g0 + 1024, lds + sub + 1024);
        const char* g1 = gBmat + (size_t)tileJ(1) * 8192 + sub + laneoff;
        gload_lds16(g1,        lds + 8192 + sub);
        gload_lds16(g1 + 1024, lds + 8192 + sub + 1024);
    }

    // A fragments / row norms for a strip
    auto loadA = [&](int strip, bf16x8 (&af)[2][2], f32x4 (&nc)[2]) {
        int rowBase = strip * 64 + wr * 32;
        #pragma unroll
        for (int mt = 0; mt < 2; ++mt)
            #pragma unroll
            for (int kc = 0; kc < 2; ++kc)
                af[mt][kc] = *reinterpret_cast<const bf16x8*>(
                    A + (size_t)(rowBase + mt * 16 + r) * D + kc * 32 + q * 8);
        #pragma unroll
        for (int mt = 0; mt < 2; ++mt)
            #pragma unroll
            for (int e = 0; e < 4; ++e)
                nc[mt][e] = -ca[rowBase + mt * 16 + q * 4 + e];
    };

    f32x4 lsum = (f32x4)0.0f;
    unsigned rb = 0;   // read-buffer byte offset: 0 / 8192 / 16384

    auto doIter = [&](int u, bf16x8 (&af)[2][2], f32x4 (&nc)[2]) {
        // Tile u landed when all but the newest 2 VMEM events (last iter's
        // stage pair) retired; barrier publishes it block-wide.
        asm volatile("s_waitcnt vmcnt(2)" ::: "memory");
        __builtin_amdgcn_s_barrier();
        asm volatile("" ::: "memory");

        int j = tileJ(u);
        const float* cbj = cb + j * 64 + wc * 32 + r;
        float cb0 = cbj[0], cb1 = cbj[16];

        // Stage tile min(u+2, nTot-1) into buffer (u+2)%3 (clamped re-stage
        // keeps the vmcnt ledger uniform; that buffer is never read again).
        unsigned sb = rb + 16384; if (sb >= 24576) sb -= 24576;
        int un = (u + 2 <= nTot - 1) ? (u + 2) : (nTot - 1);
        const char* gs = gBmat + (size_t)tileJ(un) * 8192 + sub + laneoff;
        gload_lds16(gs,        lds + sb + sub);
        gload_lds16(gs + 1024, lds + sb + sub + 1024);

        const char* lb = lds + rb;
        bf16x8 bfrag[2][2];
        bfrag[0][0] = *reinterpret_cast<const bf16x8*>(lb + off0);
        bfrag[0][1] = *reinterpret_cast<const bf16x8*>(lb + off1);
        bfrag[1][0] = *reinterpret_cast<const bf16x8*>(lb + 2048 + off0);
        bfrag[1][1] = *reinterpret_cast<const bf16x8*>(lb + 2048 + off1);

        // C-init carries the norm bias: acc = -(na + nb); result = log2(term)
        f32x4 acc[2][2];
        acc[0][0] = nc[0] - cb0; acc[0][1] = nc[0] - cb1;
        acc[1][0] = nc[1] - cb0; acc[1][1] = nc[1] - cb1;

        #pragma unroll
        for (int kc = 0; kc < 2; ++kc)
            #pragma unroll
            for (int mt = 0; mt < 2; ++mt)
                #pragma unroll
                for (int nt = 0; nt < 2; ++nt)
                    acc[mt][nt] = __builtin_amdgcn_mfma_f32_16x16x32_bf16(
                        af[mt][kc], bfrag[nt][kc], acc[mt][nt], 0, 0, 0);

        // Negligible-tile skip (max3-fusable tree over the 16 lane values)
        float m0 = fmaxf(fmaxf(acc[0][0][0], acc[0][0][1]), acc[0][0][2]);
        float m1 = fmaxf(fmaxf(acc[0][0][3], acc[0][1][0]), acc[0][1][1]);
        float m2 = fmaxf(fmaxf(acc[0][1][2], acc[0][1][3]), acc[1][0][0]);
        float m3 = fmaxf(fmaxf(acc[1][0][1], acc[1][0][2]), acc[1][0][3]);
        float m4 = fmaxf(fmaxf(acc[1][1][0], acc[1][1][1]), acc[1][1][2]);
        float m5 = fmaxf(fmaxf(m0, m1), m2);
        float m6 = fmaxf(fmaxf(m3, m4), acc[1][1][3]);
        float m  = fmaxf(m5, m6);

        if (__any(m > -25.0f)) {
            float fac = (u == diagU) ? 1.0f : wBase;
            #pragma unroll
            for (int mt = 0; mt < 2; ++mt) {
                #pragma unroll
                for (int nt = 0; nt < 2; ++nt) {
                    f32x4 ex;
                    #pragma unroll
                    for (int e = 0; e < 4; ++e)
                        ex[e] = __builtin_amdgcn_exp2f(acc[mt][nt][e]);
                    lsum += ex * fac;
                }
            }
        }

        rb += 8192; if (rb >= 24576) rb = 0;
    };

    {
        bf16x8 afragA[2][2]; f32x4 ncamA[2];
        loadA(stripA, afragA, ncamA);
        for (int u = 0; u < nA; ++u) doIter(u, afragA, ncamA);
    }
    if (nA < nTot) {
        bf16x8 afragB[2][2]; f32x4 ncamB[2];
        loadA(stripB, afragB, ncamB);
        for (int u = nA; u < nTot; ++u) doIter(u, afragB, ncamB);
    }

    float ls = lsum[0] + lsum[1] + lsum[2] + lsum[3];
    #pragma unroll
    for (int off = 32; off; off >>= 1) ls += __shfl_xor(ls, off);
    if (lane == 0) wsum[w] = ls;
    __syncthreads();
    if (tid == 0) {
        atomicAdd(&accs[p], wsum[0] + wsum[1] + wsum[2] + wsum[3]);
        __threadfence();
        unsigned old = atomicAdd(cnt, 1u);
        if (old == 1152u - 1u) {
            __threadfence();
            double s[6];
            #pragma unroll
            for (int i = 0; i < 6; ++i) s[i] = (double)atomicAdd(&accs[i], 0.0f);
            double inv = 1.0 / (8192.0 * 8192.0 * 3.5449077018110318);
            double mxx = s[0] * inv, mzz = s[1] * inv, mxz = s[2] * inv;
            double mxy = s[3] * inv, myy = s[4] * inv, myz = s[5] * inv;
            double r1 = log(3.0 * sqrt(mxx * mzz + 1e-5) / (mxz + 1e-5));
            double r2 = log(3.0 * sqrt(myy * mzz + 1e-5) / (myz + 1e-5));
            double r3 = log(3.0 * sqrt(mxx * myy + 1e-5) / (mxy + 1e-5));
            out[0] = (float)(10.0 * r1 + r2 + 10.0 * r3);
        }
    }
}

extern "C" void kernel_launch(void* const* d_in, const int* in_sizes, int n_in,
                              void* d_out, int out_size, void* d_ws, size_t ws_size,
                              hipStream_t stream) {
    const float* X = (const float*)d_in[0];
    const float* Y = (const float*)d_in[1];
    const float* Z = (const float*)d_in[2];
    char* ws = (char*)d_ws;
    unsigned short* bmat = (unsigned short*)ws;                       // 3 MB
    float* nscl = (float*)(ws + (size_t)3 * N * D * 2);               // 3*8192 f32
    float* accs = (float*)(ws + (size_t)3 * N * D * 2 + (size_t)3 * N * 4); // 8 slots
    unsigned int* cnt = (unsigned int*)(accs + 6);
    float* out = (float*)d_out;

    hipLaunchKernelGGL(convert_norm, dim3(3 * N / 4), dim3(256), 0, stream,
                       X, Y, Z, bmat, nscl, accs);
    hipLaunchKernelGGL(gram_kernel, dim3(1152), dim3(256), 0, stream,
                       bmat, nscl, accs, cnt, out);
}